// Round 8
// baseline (70.097 us; speedup 1.0000x reference)
//
#include <hip/hip_runtime.h>
#include <hip/hip_bf16.h>

// GridToMeshEncoder R8: fused kernel, 2 tiles/block, software-pipelined:
//   tile1 row-loads issue right after tile0's comb is built and fly during
//   tile0's GEMM1/GEMM2; tile0's stores drain during tile1's compute.
// Gather pattern, LDS swizzle, GEMM layouts identical to R6 (validated).

constexpr int kNLat  = 721;
constexpr int kNLon  = 1440;
constexpr long long kNPix = (long long)kNLat * kNLon;   // 1038240
constexpr int kMesh  = 40962;
constexpr int kCIn   = 64;
constexpr int kFeat  = 4;
constexpr int kDIn   = kCIn + kFeat;                    // 68
constexpr int kHid   = 256;
constexpr int kOut   = 256;
constexpr int kBatch = 2;

constexpr int kPts    = kBatch * kMesh;                 // 81924
constexpr int kPtsPad = (kPts + 63) & ~63;              // 81984

typedef __attribute__((ext_vector_type(8))) short bf16x8;
typedef __attribute__((ext_vector_type(4))) float f32x4;

// ws layout (ushort units): wsA1 = W1^T A-frags [rt:16][ks:3][lane:64][j:8]
//                           wsB2 = W2   frags   [ct:16][ks:8][lane:64][j:8]
constexpr int    WSA1_N   = 16 * 3 * 64 * 8;            // 24576
constexpr int    WSB2_N   = 16 * 8 * 64 * 8;            // 65536
constexpr size_t WS_BYTES = (size_t)(WSA1_N + WSB2_N) * 2;  // 180224

constexpr int MP    = 64;                       // points per tile
constexpr int NBLK2 = (kPtsPad + 2 * MP - 1) / (2 * MP);    // 641
constexpr int CSTR  = 128;                      // comb row stride (ushort): 256 B
constexpr int HSTR  = 256;                      // hbuf row stride (ushort): 512 B

__device__ inline ushort f2b(float v) {
    __hip_bfloat16 h = __float2bfloat16(v);
    return *reinterpret_cast<ushort*>(&h);
}

// XOR swizzle on 16B granules within a row (reads/writes paired; R6-validated)
__device__ inline int cswz(int r, int c) { return r * CSTR + (c ^ ((r & 7) << 3)); }
__device__ inline int hswz(int r, int c) { return r * HSTR + (c ^ ((r & 7) << 3)); }

// ---------------- prep: pack W1/W2 into frag-ordered bf16 ----------------
__global__ __launch_bounds__(256)
void g2m_prep(const float* __restrict__ W1, const float* __restrict__ W2,
              ushort* __restrict__ ws) {
    const int tid = blockIdx.x * 256 + threadIdx.x;
    if (tid < 3072) {                       // wsA1: A[i=hid][k] = W1[k][hid]
        const int l  = tid & 63;
        const int g  = tid >> 6;            // g = rt*3 + ks
        const int ks = g % 3;
        const int rt = g / 3;
        const int hid = rt * 16 + (l & 15);
        const int k0  = ks * 32 + (l >> 4) * 8;
        ushort tmp[8];
        #pragma unroll
        for (int j = 0; j < 8; ++j) {
            const int k = k0 + j;
            tmp[j] = f2b(k < kDIn ? W1[(size_t)k * kHid + hid] : 0.f);
        }
        *reinterpret_cast<bf16x8*>(ws + (size_t)tid * 8) =
            *reinterpret_cast<bf16x8*>(tmp);
    } else if (tid < 11264) {               // wsB2: [ct][ks][lane][8] = W2[k][col]
        const int q  = tid - 3072;
        const int l  = q & 63;
        const int g  = q >> 6;              // g = ct*8 + ks
        const int ks = g % 8;
        const int ct = g / 8;
        const int col = ct * 16 + (l & 15);
        const int k0  = ks * 32 + (l >> 4) * 8;
        ushort tmp[8];
        #pragma unroll
        for (int j = 0; j < 8; ++j) {
            const int k = k0 + j;
            tmp[j] = f2b(W2[(size_t)k * kOut + col]);
        }
        *reinterpret_cast<bf16x8*>(ws + (size_t)(WSA1_N + q * 8)) =
            *reinterpret_cast<bf16x8*>(tmp);
    }
}

// ---------------- per-tile register staging ----------------
struct GRegs {
    float4 rr[4][4];    // [it][corner]
    float4 wt[4];
    float  mf0[4], mf1[4];
};

__device__ inline void load_meta(const int* __restrict__ indices,
                                 const float* __restrict__ weights,
                                 const float* __restrict__ mfeat,
                                 int p0, int w, int l15, int l4,
                                 int4 (&id)[4], GRegs& g) {
    #pragma unroll
    for (int it = 0; it < 4; ++it) {
        const int p = p0 + w * 16 + it * 4 + l4;
        id[it] = int4{0, 0, 0, 0};
        g.wt[it] = float4{0.f, 0.f, 0.f, 0.f};
        g.mf0[it] = 0.f; g.mf1[it] = 0.f;
        if (p < kPts) {
            const int b = (p >= kMesh) ? 1 : 0;
            const int m = p - b * kMesh;
            id[it] = *reinterpret_cast<const int4*>(indices + (size_t)m * 4);
            id[it].x += b ? (int)kNPix : 0;   // fold batch offset into row idx
            id[it].y += b ? (int)kNPix : 0;
            id[it].z += b ? (int)kNPix : 0;
            id[it].w += b ? (int)kNPix : 0;
            g.wt[it] = *reinterpret_cast<const float4*>(weights + (size_t)m * 4);
            if (l15 < 2) {
                g.mf0[it] = mfeat[(size_t)m * kFeat + l15 * 2];
                g.mf1[it] = mfeat[(size_t)m * kFeat + l15 * 2 + 1];
            }
        }
    }
}

__device__ inline void load_rows(const float* __restrict__ grid,
                                 int p0, int w, int l15, int l4,
                                 const int4 (&id)[4], GRegs& g) {
    #pragma unroll
    for (int it = 0; it < 4; ++it) {
        const int p = p0 + w * 16 + it * 4 + l4;
        g.rr[it][0] = g.rr[it][1] = g.rr[it][2] = g.rr[it][3] = float4{0.f, 0.f, 0.f, 0.f};
        if (p < kPts) {
            g.rr[it][0] = *reinterpret_cast<const float4*>(grid + (size_t)id[it].x * kCIn + l15 * 4);
            g.rr[it][1] = *reinterpret_cast<const float4*>(grid + (size_t)id[it].y * kCIn + l15 * 4);
            g.rr[it][2] = *reinterpret_cast<const float4*>(grid + (size_t)id[it].z * kCIn + l15 * 4);
            g.rr[it][3] = *reinterpret_cast<const float4*>(grid + (size_t)id[it].w * kCIn + l15 * 4);
        }
    }
}

__device__ inline void reduce_tile(const GRegs& g, ushort* comb,
                                   int w, int l15, int l4) {
    #pragma unroll
    for (int it = 0; it < 4; ++it) {
        const int row = w * 16 + it * 4 + l4;
        const float4 wt = g.wt[it];
        float4 acc;
        acc.x = fmaf(wt.x, g.rr[it][0].x, fmaf(wt.y, g.rr[it][1].x, fmaf(wt.z, g.rr[it][2].x, wt.w * g.rr[it][3].x)));
        acc.y = fmaf(wt.x, g.rr[it][0].y, fmaf(wt.y, g.rr[it][1].y, fmaf(wt.z, g.rr[it][2].y, wt.w * g.rr[it][3].y)));
        acc.z = fmaf(wt.x, g.rr[it][0].z, fmaf(wt.y, g.rr[it][1].z, fmaf(wt.z, g.rr[it][2].z, wt.w * g.rr[it][3].z)));
        acc.w = fmaf(wt.x, g.rr[it][0].w, fmaf(wt.y, g.rr[it][1].w, fmaf(wt.z, g.rr[it][2].w, wt.w * g.rr[it][3].w)));
        ushort4 pk;
        pk.x = f2b(acc.x); pk.y = f2b(acc.y); pk.z = f2b(acc.z); pk.w = f2b(acc.w);
        *reinterpret_cast<ushort4*>(&comb[cswz(row, l15 * 4)]) = pk;     // cols 0..63
        ushort2 ft;                                                       // cols 64..95
        ft.x = f2b(g.mf0[it]); ft.y = f2b(g.mf1[it]);
        *reinterpret_cast<ushort2*>(&comb[cswz(row, 64 + l15 * 2)]) = ft;
    }
}

__device__ inline void gemm1(const ushort* comb, ushort* hbuf,
                             const ushort* __restrict__ ws,
                             const float* __restrict__ b1,
                             int w, int lane, int l15, int l4) {
    f32x4 acc1[4][4];                       // [r(hid-tile)][mt(pt-tile)]
    #pragma unroll
    for (int r = 0; r < 4; ++r)
        #pragma unroll
        for (int mt = 0; mt < 4; ++mt) acc1[r][mt] = (f32x4)0.f;

    #pragma unroll
    for (int ks = 0; ks < 3; ++ks) {
        bf16x8 af[4], bfr[4];
        #pragma unroll
        for (int r = 0; r < 4; ++r) {
            const int rt = w * 4 + r;
            af[r] = *reinterpret_cast<const bf16x8*>(
                        ws + (size_t)((rt * 3 + ks) * 64 + lane) * 8);
        }
        #pragma unroll
        for (int mt = 0; mt < 4; ++mt)
            bfr[mt] = *reinterpret_cast<const bf16x8*>(
                        &comb[cswz(mt * 16 + l15, ks * 32 + l4 * 8)]);
        #pragma unroll
        for (int r = 0; r < 4; ++r)
            #pragma unroll
            for (int mt = 0; mt < 4; ++mt)
                acc1[r][mt] = __builtin_amdgcn_mfma_f32_16x16x32_bf16(
                                  af[r], bfr[mt], acc1[r][mt], 0, 0, 0);
    }

    #pragma unroll
    for (int r = 0; r < 4; ++r) {
        const int hid0 = (w * 4 + r) * 16 + l4 * 4;
        const float4 bv = *reinterpret_cast<const float4*>(b1 + hid0);
        #pragma unroll
        for (int mt = 0; mt < 4; ++mt) {
            const int m = mt * 16 + l15;
            ushort4 hv;
            hv.x = f2b(fmaxf(acc1[r][mt][0] + bv.x, 0.f));
            hv.y = f2b(fmaxf(acc1[r][mt][1] + bv.y, 0.f));
            hv.z = f2b(fmaxf(acc1[r][mt][2] + bv.z, 0.f));
            hv.w = f2b(fmaxf(acc1[r][mt][3] + bv.w, 0.f));
            *reinterpret_cast<ushort4*>(&hbuf[hswz(m, hid0)]) = hv;
        }
    }
}

__device__ inline void gemm2(const ushort* hbuf,
                             const ushort* __restrict__ ws,
                             const float* __restrict__ b2,
                             float* __restrict__ out,
                             int p0, int w, int lane, int l15, int l4) {
    f32x4 acc2[4][4];                       // [mt(pt-tile)][c(outcol-tile)]
    #pragma unroll
    for (int mt = 0; mt < 4; ++mt)
        #pragma unroll
        for (int c = 0; c < 4; ++c) acc2[mt][c] = (f32x4)0.f;

    #pragma unroll
    for (int ks = 0; ks < 8; ++ks) {
        bf16x8 hf[4], wf[4];
        #pragma unroll
        for (int mt = 0; mt < 4; ++mt)
            hf[mt] = *reinterpret_cast<const bf16x8*>(
                        &hbuf[hswz(mt * 16 + l15, ks * 32 + l4 * 8)]);
        #pragma unroll
        for (int c = 0; c < 4; ++c) {
            const int ct = w * 4 + c;
            wf[c] = *reinterpret_cast<const bf16x8*>(
                        ws + (size_t)(WSA1_N + ((ct * 8 + ks) * 64 + lane) * 8));
        }
        #pragma unroll
        for (int mt = 0; mt < 4; ++mt)
            #pragma unroll
            for (int c = 0; c < 4; ++c)
                acc2[mt][c] = __builtin_amdgcn_mfma_f32_16x16x32_bf16(
                                  wf[c], hf[mt], acc2[mt][c], 0, 0, 0);
    }

    #pragma unroll
    for (int c = 0; c < 4; ++c) {
        const int col0 = (w * 4 + c) * 16 + l4 * 4;
        const float4 bv = *reinterpret_cast<const float4*>(b2 + col0);
        #pragma unroll
        for (int mt = 0; mt < 4; ++mt) {
            const int p = p0 + mt * 16 + l15;
            if (p < kPts) {
                float4 o;
                o.x = acc2[mt][c][0] + bv.x;
                o.y = acc2[mt][c][1] + bv.y;
                o.z = acc2[mt][c][2] + bv.z;
                o.w = acc2[mt][c][3] + bv.w;
                *reinterpret_cast<float4*>(out + (size_t)p * kOut + col0) = o;
            }
        }
    }
}

// ---------------- fused pipelined kernel: 2 tiles per block ----------------
__global__ __launch_bounds__(256, 2)
void g2m_fused5(const float* __restrict__ grid,
                const float* __restrict__ mfeat,
                const int*   __restrict__ indices,
                const float* __restrict__ weights,
                const float* __restrict__ b1,
                const float* __restrict__ b2,
                const ushort* __restrict__ ws,
                float* __restrict__ out)
{
    __shared__ __align__(16) ushort comb0[MP * CSTR];   // 16384 B
    __shared__ __align__(16) ushort comb1[MP * CSTR];   // 16384 B
    __shared__ __align__(16) ushort hbuf[MP * HSTR];    // 32768 B

    const int t    = threadIdx.x;
    const int lane = t & 63;
    const int w    = t >> 6;                    // wave id 0..3
    const int pa   = blockIdx.x * (2 * MP);     // tile0 base
    const int pb   = pa + MP;                   // tile1 base
    const int l15  = lane & 15;
    const int l4   = lane >> 4;

    int4  id0[4], id1[4];
    GRegs g0, g1;

    // meta for both tiles upfront; rows for tile0
    load_meta(indices, weights, mfeat, pa, w, l15, l4, id0, g0);
    load_meta(indices, weights, mfeat, pb, w, l15, l4, id1, g1);
    load_rows(grid, pa, w, l15, l4, id0, g0);

    reduce_tile(g0, comb0, w, l15, l4);         // waits tile0 rows
    __syncthreads();                            // B1: comb0 ready

    load_rows(grid, pb, w, l15, l4, id1, g1);   // fly during tile0 compute

    gemm1(comb0, hbuf, ws, b1, w, lane, l15, l4);
    __syncthreads();                            // B2: hbuf(T0) ready
    gemm2(hbuf, ws, b2, out, pa, w, lane, l15, l4);   // stores T0 drain async

    reduce_tile(g1, comb1, w, l15, l4);         // waits tile1 rows (covered)
    __syncthreads();                            // B3: comb1 ready, hbuf reads done

    gemm1(comb1, hbuf, ws, b1, w, lane, l15, l4);
    __syncthreads();                            // B4: hbuf(T1) ready
    gemm2(hbuf, ws, b2, out, pb, w, lane, l15, l4);
}

extern "C" void kernel_launch(void* const* d_in, const int* in_sizes, int n_in,
                              void* d_out, int out_size, void* d_ws, size_t ws_size,
                              hipStream_t stream) {
    const float* grid    = (const float*)d_in[0];
    const float* mfeat   = (const float*)d_in[1];
    const int*   indices = (const int*)d_in[2];
    const float* weights = (const float*)d_in[3];
    const float* W1      = (const float*)d_in[4];
    const float* b1      = (const float*)d_in[5];
    const float* W2      = (const float*)d_in[6];
    const float* b2      = (const float*)d_in[7];
    float* o = (float*)d_out;

    if (ws_size >= WS_BYTES) {
        ushort* ws = (ushort*)d_ws;
        g2m_prep<<<44, 256, 0, stream>>>(W1, W2, ws);
        g2m_fused5<<<NBLK2, 256, 0, stream>>>(grid, mfeat, indices, weights,
                                              b1, b2, ws, o);
    }
}

// Round 9
// 54.045 us; speedup vs baseline: 1.2970x; 1.2970x over previous
//
#include <hip/hip_runtime.h>
#include <hip/hip_bf16.h>

// GridToMeshEncoder R9: R5/R6 fused structure with MP=32 (half tile) for
// 5-6 resident blocks/CU (was 3) -> better cross-block phase overlap.
//   phase1: vectorized gather (2 its x 4 pts/wave) -> swizzled comb LDS (8KB)
//   phase2: GEMM1 h^T = W1^T * comb^T -> swizzled hbuf LDS (16KB)
//   phase3: GEMM2^T out^T = W2^T * h^T -> float4 stores
// prep kernel packs W1/W2 into MFMA fragment order (L2-resident, ~180 KB).

constexpr int kNLat  = 721;
constexpr int kNLon  = 1440;
constexpr long long kNPix = (long long)kNLat * kNLon;   // 1038240
constexpr int kMesh  = 40962;
constexpr int kCIn   = 64;
constexpr int kFeat  = 4;
constexpr int kDIn   = kCIn + kFeat;                    // 68
constexpr int kHid   = 256;
constexpr int kOut   = 256;
constexpr int kBatch = 2;

constexpr int kPts    = kBatch * kMesh;                 // 81924
constexpr int kPtsPad = (kPts + 63) & ~63;              // 81984

typedef __attribute__((ext_vector_type(8))) short bf16x8;
typedef __attribute__((ext_vector_type(4))) float f32x4;

// ws layout (ushort units): wsA1 = W1^T A-frags [rt:16][ks:3][lane:64][j:8]
//                           wsB2 = W2   frags   [ct:16][ks:8][lane:64][j:8]
constexpr int    WSA1_N   = 16 * 3 * 64 * 8;            // 24576
constexpr int    WSB2_N   = 16 * 8 * 64 * 8;            // 65536
constexpr size_t WS_BYTES = (size_t)(WSA1_N + WSB2_N) * 2;  // 180224

constexpr int MP    = 32;                       // points per block (halved)
constexpr int NBLKB = kPtsPad / MP;             // 2562
constexpr int CSTR  = 128;                      // comb row stride (ushort): 256 B
constexpr int HSTR  = 256;                      // hbuf row stride (ushort): 512 B

__device__ inline ushort f2b(float v) {
    __hip_bfloat16 h = __float2bfloat16(v);
    return *reinterpret_cast<ushort*>(&h);
}

// XOR swizzle on 16B granules within a row (reads/writes paired; R6-validated)
__device__ inline int cswz(int r, int c) { return r * CSTR + (c ^ ((r & 7) << 3)); }
__device__ inline int hswz(int r, int c) { return r * HSTR + (c ^ ((r & 7) << 3)); }

// ---------------- prep: pack W1/W2 into frag-ordered bf16 ----------------
__global__ __launch_bounds__(256)
void g2m_prep(const float* __restrict__ W1, const float* __restrict__ W2,
              ushort* __restrict__ ws) {
    const int tid = blockIdx.x * 256 + threadIdx.x;
    if (tid < 3072) {                       // wsA1: A[i=hid][k] = W1[k][hid]
        const int l  = tid & 63;
        const int g  = tid >> 6;            // g = rt*3 + ks
        const int ks = g % 3;
        const int rt = g / 3;
        const int hid = rt * 16 + (l & 15);
        const int k0  = ks * 32 + (l >> 4) * 8;
        ushort tmp[8];
        #pragma unroll
        for (int j = 0; j < 8; ++j) {
            const int k = k0 + j;
            tmp[j] = f2b(k < kDIn ? W1[(size_t)k * kHid + hid] : 0.f);
        }
        *reinterpret_cast<bf16x8*>(ws + (size_t)tid * 8) =
            *reinterpret_cast<bf16x8*>(tmp);
    } else if (tid < 11264) {               // wsB2: [ct][ks][lane][8] = W2[k][col]
        const int q  = tid - 3072;
        const int l  = q & 63;
        const int g  = q >> 6;              // g = ct*8 + ks
        const int ks = g % 8;
        const int ct = g / 8;
        const int col = ct * 16 + (l & 15);
        const int k0  = ks * 32 + (l >> 4) * 8;
        ushort tmp[8];
        #pragma unroll
        for (int j = 0; j < 8; ++j) {
            const int k = k0 + j;
            tmp[j] = f2b(W2[(size_t)k * kOut + col]);
        }
        *reinterpret_cast<bf16x8*>(ws + (size_t)(WSA1_N + q * 8)) =
            *reinterpret_cast<bf16x8*>(tmp);
    }
}

// ---------------- fused: gather -> GEMM1 -> GEMM2^T -> out ----------------
__global__ __launch_bounds__(256, 5)
void g2m_fused6(const float* __restrict__ grid,
                const float* __restrict__ mfeat,
                const int*   __restrict__ indices,
                const float* __restrict__ weights,
                const float* __restrict__ b1,
                const float* __restrict__ b2,
                const ushort* __restrict__ ws,
                float* __restrict__ out)
{
    __shared__ __align__(16) ushort comb[MP * CSTR];    // 8192 B
    __shared__ __align__(16) ushort hbuf[MP * HSTR];    // 16384 B

    const int t    = threadIdx.x;
    const int lane = t & 63;
    const int w    = t >> 6;                    // wave id 0..3
    const int p0   = blockIdx.x * MP;
    const int l15  = lane & 15;
    const int l4   = lane >> 4;

    // ---- phase 1: gather, 4 points per wave-iteration, 2 iterations ----
    {
        const int q = l4;                       // point-in-group 0..3
        #pragma unroll
        for (int it = 0; it < 2; ++it) {
            const int row = w * 8 + it * 4 + q;     // local row 0..31
            const int p   = p0 + row;
            float4 acc = {0.f, 0.f, 0.f, 0.f};
            float mf0 = 0.f, mf1 = 0.f;
            if (p < kPts) {
                const int b = (p >= kMesh) ? 1 : 0;
                const int m = p - b * kMesh;
                const int4   id = *reinterpret_cast<const int4*>(indices + (size_t)m * 4);
                const float4 wt = *reinterpret_cast<const float4*>(weights + (size_t)m * 4);
                const float* gb = grid + (size_t)b * (size_t)(kNPix * kCIn);
                const float4 r0 = *reinterpret_cast<const float4*>(gb + (size_t)id.x * kCIn + l15 * 4);
                const float4 r1 = *reinterpret_cast<const float4*>(gb + (size_t)id.y * kCIn + l15 * 4);
                const float4 r2 = *reinterpret_cast<const float4*>(gb + (size_t)id.z * kCIn + l15 * 4);
                const float4 r3 = *reinterpret_cast<const float4*>(gb + (size_t)id.w * kCIn + l15 * 4);
                acc.x = fmaf(wt.x, r0.x, fmaf(wt.y, r1.x, fmaf(wt.z, r2.x, wt.w * r3.x)));
                acc.y = fmaf(wt.x, r0.y, fmaf(wt.y, r1.y, fmaf(wt.z, r2.y, wt.w * r3.y)));
                acc.z = fmaf(wt.x, r0.z, fmaf(wt.y, r1.z, fmaf(wt.z, r2.z, wt.w * r3.z)));
                acc.w = fmaf(wt.x, r0.w, fmaf(wt.y, r1.w, fmaf(wt.z, r2.w, wt.w * r3.w)));
                if (l15 < 2) {
                    mf0 = mfeat[(size_t)m * kFeat + l15 * 2];
                    mf1 = mfeat[(size_t)m * kFeat + l15 * 2 + 1];
                }
            }
            ushort4 pk;
            pk.x = f2b(acc.x); pk.y = f2b(acc.y); pk.z = f2b(acc.z); pk.w = f2b(acc.w);
            *reinterpret_cast<ushort4*>(&comb[cswz(row, l15 * 4)]) = pk;   // cols 0..63
            ushort2 ft;                                                     // cols 64..95
            ft.x = f2b(mf0); ft.y = f2b(mf1);
            *reinterpret_cast<ushort2*>(&comb[cswz(row, 64 + l15 * 2)]) = ft;
        }
    }
    __syncthreads();

    // ---- phase 2: GEMM1  h^T = W1^T @ comb^T ----
    {
        f32x4 acc1[4][2];                       // [r(hid-tile)][mt(pt-tile)]
        #pragma unroll
        for (int r = 0; r < 4; ++r)
            #pragma unroll
            for (int mt = 0; mt < 2; ++mt) acc1[r][mt] = (f32x4)0.f;

        #pragma unroll
        for (int ks = 0; ks < 3; ++ks) {
            bf16x8 af[4], bfr[2];
            #pragma unroll
            for (int r = 0; r < 4; ++r) {
                const int rt = w * 4 + r;
                af[r] = *reinterpret_cast<const bf16x8*>(
                            ws + (size_t)((rt * 3 + ks) * 64 + lane) * 8);
            }
            #pragma unroll
            for (int mt = 0; mt < 2; ++mt)
                bfr[mt] = *reinterpret_cast<const bf16x8*>(
                            &comb[cswz(mt * 16 + l15, ks * 32 + l4 * 8)]);
            #pragma unroll
            for (int r = 0; r < 4; ++r)
                #pragma unroll
                for (int mt = 0; mt < 2; ++mt)
                    acc1[r][mt] = __builtin_amdgcn_mfma_f32_16x16x32_bf16(
                                      af[r], bfr[mt], acc1[r][mt], 0, 0, 0);
        }

        // bias + relu -> hbuf[m][hid] (bf16, swizzled)
        #pragma unroll
        for (int r = 0; r < 4; ++r) {
            const int hid0 = (w * 4 + r) * 16 + l4 * 4;
            const float4 bv = *reinterpret_cast<const float4*>(b1 + hid0);
            #pragma unroll
            for (int mt = 0; mt < 2; ++mt) {
                const int m = mt * 16 + l15;
                ushort4 hv;
                hv.x = f2b(fmaxf(acc1[r][mt][0] + bv.x, 0.f));
                hv.y = f2b(fmaxf(acc1[r][mt][1] + bv.y, 0.f));
                hv.z = f2b(fmaxf(acc1[r][mt][2] + bv.z, 0.f));
                hv.w = f2b(fmaxf(acc1[r][mt][3] + bv.w, 0.f));
                *reinterpret_cast<ushort4*>(&hbuf[hswz(m, hid0)]) = hv;
            }
        }
    }
    __syncthreads();

    // ---- phase 3: GEMM2 transposed  out^T = W2^T @ h^T ----
    {
        f32x4 acc2[2][4];                       // [mt(pt-tile)][c(outcol-tile)]
        #pragma unroll
        for (int mt = 0; mt < 2; ++mt)
            #pragma unroll
            for (int c = 0; c < 4; ++c) acc2[mt][c] = (f32x4)0.f;

        #pragma unroll
        for (int ks = 0; ks < 8; ++ks) {
            bf16x8 hf[2], wf[4];
            #pragma unroll
            for (int mt = 0; mt < 2; ++mt)
                hf[mt] = *reinterpret_cast<const bf16x8*>(
                            &hbuf[hswz(mt * 16 + l15, ks * 32 + l4 * 8)]);
            #pragma unroll
            for (int c = 0; c < 4; ++c) {
                const int ct = w * 4 + c;
                wf[c] = *reinterpret_cast<const bf16x8*>(
                            ws + (size_t)(WSA1_N + ((ct * 8 + ks) * 64 + lane) * 8));
            }
            #pragma unroll
            for (int mt = 0; mt < 2; ++mt)
                #pragma unroll
                for (int c = 0; c < 4; ++c)
                    acc2[mt][c] = __builtin_amdgcn_mfma_f32_16x16x32_bf16(
                                      wf[c], hf[mt], acc2[mt][c], 0, 0, 0);
        }

        // epilogue: lane holds 4 consecutive out cols for one point -> float4
        #pragma unroll
        for (int c = 0; c < 4; ++c) {
            const int col0 = (w * 4 + c) * 16 + l4 * 4;
            const float4 bv = *reinterpret_cast<const float4*>(b2 + col0);
            #pragma unroll
            for (int mt = 0; mt < 2; ++mt) {
                const int p = p0 + mt * 16 + l15;
                if (p < kPts) {
                    float4 o;
                    o.x = acc2[mt][c][0] + bv.x;
                    o.y = acc2[mt][c][1] + bv.y;
                    o.z = acc2[mt][c][2] + bv.z;
                    o.w = acc2[mt][c][3] + bv.w;
                    *reinterpret_cast<float4*>(out + (size_t)p * kOut + col0) = o;
                }
            }
        }
    }
}

extern "C" void kernel_launch(void* const* d_in, const int* in_sizes, int n_in,
                              void* d_out, int out_size, void* d_ws, size_t ws_size,
                              hipStream_t stream) {
    const float* grid    = (const float*)d_in[0];
    const float* mfeat   = (const float*)d_in[1];
    const int*   indices = (const int*)d_in[2];
    const float* weights = (const float*)d_in[3];
    const float* W1      = (const float*)d_in[4];
    const float* b1      = (const float*)d_in[5];
    const float* W2      = (const float*)d_in[6];
    const float* b2      = (const float*)d_in[7];
    float* o = (float*)d_out;

    if (ws_size >= WS_BYTES) {
        ushort* ws = (ushort*)d_ws;
        g2m_prep<<<44, 256, 0, stream>>>(W1, W2, ws);
        g2m_fused6<<<NBLKB, 256, 0, stream>>>(grid, mfeat, indices, weights,
                                              b1, b2, ws, o);
    }
}